// Round 1
// baseline (308.021 us; speedup 1.0000x reference)
//
#include <hip/hip_runtime.h>
#include <float.h>

// Detect (SSD post-processing) for MI355X.
// Reference: per (batch b, class c in 1..20):
//   scores = conf[b,:,c]; pass = scores > 0.95
//   candidates = stable top-600 of passing scores (desc score, asc index ties)
//   greedy NMS: i ascending, suppress j>i with iou(i,j) > 0.45
//   output [200,5]: first n=min(kept,200) slots = (score, loc[b,prior]);
//   slots >= n: (0, loc[b, first_passing_prior]); all-zero lane if none pass.
// Class 0 (background) is all zeros. prior_data is unused by the reference.

#define P_PRIORS  8732
#define C_CLASSES 21
#define B_BATCH   8
#define TOPK      200
#define MCAND     600
#define NCAP      1024   // compaction capacity; pass count ~N(437,20) -> 1024 is >29 sigma
#define CONF_T    0.95f
#define NMS_T     0.45f

__global__ __launch_bounds__(256) void detect_kernel(
    const float* __restrict__ loc,    // [B, P, 4]
    const float* __restrict__ conf,   // [B, P, C]
    float* __restrict__ out)          // [B, 21, 200, 5]
{
    const int lane = blockIdx.x;              // 0 .. B*21-1
    const int b    = lane / C_CLASSES;
    const int cls  = lane % C_CLASSES;
    const int tid  = threadIdx.x;
    float* o = out + (size_t)lane * TOPK * 5;

    if (cls == 0) {   // background class: zeros
        for (int k = tid; k < TOPK * 5; k += 256) o[k] = 0.0f;
        return;
    }

    __shared__ float s_score[NCAP];
    __shared__ int   s_idx[NCAP];
    __shared__ float s_x1[MCAND], s_y1[MCAND], s_x2[MCAND], s_y2[MCAND], s_area[MCAND];
    __shared__ unsigned char s_supp[MCAND];
    __shared__ int   s_selc[TOPK];
    __shared__ int   s_count, s_fp, s_n;

    if (tid == 0) { s_count = 0; s_fp = 0x7FFFFFFF; }
    __syncthreads();

    // ---- 1. compact passing (score, prior_idx) pairs into LDS ----
    const float* confb = conf + (size_t)b * P_PRIORS * C_CLASSES + cls;
    for (int p = tid; p < P_PRIORS; p += 256) {
        float sc = confb[(size_t)p * C_CLASSES];
        if (sc > CONF_T) {
            int pos = atomicAdd(&s_count, 1);
            if (pos < NCAP) { s_score[pos] = sc; s_idx[pos] = p; }
            atomicMin(&s_fp, p);   // fp = argmax(pass_mask) = first passing index
        }
    }
    __syncthreads();

    int cnt = s_count; if (cnt > NCAP) cnt = NCAP;

    if (cnt == 0) {   // pass_mask.any() == False -> all zeros
        for (int k = tid; k < TOPK * 5; k += 256) o[k] = 0.0f;
        return;
    }

    // pad to NCAP so bitonic sort sinks them to the end
    for (int i = cnt + tid; i < NCAP; i += 256) { s_score[i] = -FLT_MAX; s_idx[i] = 0x7FFFFFFF; }

    // ---- 2. bitonic sort: score desc, index asc on ties (matches lax.top_k) ----
    for (int k = 2; k <= NCAP; k <<= 1) {
        for (int j = k >> 1; j > 0; j >>= 1) {
            __syncthreads();
            for (int i = tid; i < NCAP; i += 256) {
                int ix = i ^ j;
                if (ix > i) {
                    float si = s_score[i], sx = s_score[ix];
                    int   ii = s_idx[i],   xi = s_idx[ix];
                    bool up         = ((i & k) == 0);
                    bool x_before_i = (sx > si) || (sx == si && xi < ii);
                    bool i_before_x = (si > sx) || (si == sx && ii < xi);
                    bool doswap = up ? x_before_i : i_before_x;
                    if (doswap) {
                        s_score[i] = sx; s_score[ix] = si;
                        s_idx[i]   = xi; s_idx[ix]   = ii;
                    }
                }
            }
        }
    }
    __syncthreads();

    const int M = cnt < MCAND ? cnt : MCAND;   // valid candidate count

    // ---- 3. gather candidate boxes ----
    const float* locb = loc + (size_t)b * P_PRIORS * 4;
    for (int i = tid; i < M; i += 256) {
        int p = s_idx[i];
        float x1 = locb[p * 4 + 0], y1 = locb[p * 4 + 1];
        float x2 = locb[p * 4 + 2], y2 = locb[p * 4 + 3];
        s_x1[i] = x1; s_y1[i] = y1; s_x2[i] = x2; s_y2[i] = y2;
        s_area[i] = (x2 - x1) * (y2 - y1);
        s_supp[i] = 0;
    }
    __syncthreads();

    // ---- 4. greedy NMS (sequential over i, parallel over j) ----
    for (int i = 0; i < M - 1; ++i) {
        if (!s_supp[i]) {       // uniform read -> no divergence
            float x1i = s_x1[i], y1i = s_y1[i], x2i = s_x2[i], y2i = s_y2[i], ai = s_area[i];
            for (int j = i + 1 + tid; j < M; j += 256) {
                float xx1 = fmaxf(x1i, s_x1[j]);
                float yy1 = fmaxf(y1i, s_y1[j]);
                float xx2 = fminf(x2i, s_x2[j]);
                float yy2 = fminf(y2i, s_y2[j]);
                float w = fmaxf(xx2 - xx1, 0.0f);
                float h = fmaxf(yy2 - yy1, 0.0f);
                float inter = w * h;
                float den = (ai + s_area[j]) - inter;   // match ref assoc order
                float iou = inter / den;                // IEEE div; NaN > t is false
                if (iou > NMS_T) s_supp[j] = 1;
            }
        }
        __syncthreads();
    }

    // ---- 5. keep-scan (order-preserving) ----
    if (tid == 0) {
        int n = 0;
        for (int i = 0; i < M; ++i) {
            if (!s_supp[i]) {
                if (n < TOPK) s_selc[n] = i;
                n++;
            }
        }
        s_n = n < TOPK ? n : TOPK;
    }
    __syncthreads();

    // ---- 6. write output [200,5] ----
    const int n  = s_n;
    const int fp = s_fp;
    for (int k = tid; k < TOPK; k += 256) {
        float sc, b0, b1, b2, b3;
        if (k < n) {
            int i = s_selc[k];
            sc = s_score[i];
            b0 = s_x1[i]; b1 = s_y1[i]; b2 = s_x2[i]; b3 = s_y2[i];
        } else {
            sc = 0.0f;   // empty slots: score 0, box of first passing prior
            b0 = locb[fp * 4 + 0]; b1 = locb[fp * 4 + 1];
            b2 = locb[fp * 4 + 2]; b3 = locb[fp * 4 + 3];
        }
        o[k * 5 + 0] = sc;
        o[k * 5 + 1] = b0; o[k * 5 + 2] = b1;
        o[k * 5 + 3] = b2; o[k * 5 + 4] = b3;
    }
}

extern "C" void kernel_launch(void* const* d_in, const int* in_sizes, int n_in,
                              void* d_out, int out_size, void* d_ws, size_t ws_size,
                              hipStream_t stream) {
    const float* loc  = (const float*)d_in[0];   // [8, 8732, 4]
    const float* conf = (const float*)d_in[1];   // [8, 8732, 21]
    // d_in[2] (prior_data) is unused by the reference computation.
    float* out = (float*)d_out;                  // [8, 21, 200, 5]
    detect_kernel<<<dim3(B_BATCH * C_CLASSES), dim3(256), 0, stream>>>(loc, conf, out);
}

// Round 2
// 185.039 us; speedup vs baseline: 1.6646x; 1.6646x over previous
//
#include <hip/hip_runtime.h>
#include <float.h>

// Detect (SSD post-processing) — matrix-NMS restructure.
// Per (b, c in 1..20): pass = conf > 0.95; stable top-600 (score desc, idx asc);
// greedy NMS iou>0.45; first min(kept,200) slots = (score, box); rest (0, box[fp]).
//
// R2: replace the 437-iteration barriered greedy loop with:
//   (a) parallel IoU bitmask matrix via __ballot (rows x 10 u64 words in LDS)
//   (b) single-wave register greedy scan (supp distributed across lanes,
//       uniform broadcast via v_readlane, 8-deep row prefetch)
//   (c) u64 packed-key bitonic sort (score_bits<<32 | ~idx) — exact lax.top_k order
//   (d) popcount-rank parallel output
// LDS: sort keys alias the bitmask buffer (s_buf) to stay under 64 KB.

#define P_PRIORS  8732
#define C_CLASSES 21
#define B_BATCH   8
#define TOPK      200
#define MCAND     600
#define NCAP      1024   // pass count ~N(437,20); 1024 is >28 sigma
#define CONF_T    0.95f
#define NMS_T     0.45f
#define NTHREADS  512

__global__ __launch_bounds__(NTHREADS) void detect_kernel(
    const float* __restrict__ loc,    // [B, P, 4]
    const float* __restrict__ conf,   // [B, P, C]
    float* __restrict__ out)          // [B, 21, 200, 5]
{
    const int lane = blockIdx.x;              // 0 .. B*21-1
    const int b    = lane / C_CLASSES;
    const int cls  = lane % C_CLASSES;
    const int tid  = threadIdx.x;
    float* o = out + (size_t)lane * TOPK * 5;

    if (cls == 0) {   // background class: zeros
        for (int k = tid; k < TOPK * 5; k += NTHREADS) o[k] = 0.0f;
        return;
    }

    // s_buf: [0..1023] u64 sort keys, then reused as bitmask rows [600][10]
    __shared__ uint64_t s_buf[MCAND * 10];          // 48000 B
    __shared__ float4   s_box[MCAND + 40];          // 640 * 16 B
    __shared__ float    s_score[MCAND + 40];
    __shared__ uint64_t s_suppw[10];
    __shared__ uint64_t s_keepw[10];
    __shared__ int      s_prefix[10];
    __shared__ int      s_count, s_fp, s_n;

    if (tid == 0) { s_count = 0; s_fp = 0x7FFFFFFF; }
    __syncthreads();

    const float* confb = conf + (size_t)b * P_PRIORS * C_CLASSES + cls;
    const float* locb  = loc  + (size_t)b * P_PRIORS * 4;

    // ---- 1. compact passing priors as packed keys ----
    for (int p = tid; p < P_PRIORS; p += NTHREADS) {
        float sc = confb[(size_t)p * C_CLASSES];
        if (sc > CONF_T) {
            int pos = atomicAdd(&s_count, 1);
            if (pos < NCAP)
                s_buf[pos] = ((uint64_t)__float_as_uint(sc) << 32) | (uint32_t)(~(uint32_t)p);
            atomicMin(&s_fp, p);
        }
    }
    __syncthreads();

    int cnt = s_count; if (cnt > NCAP) cnt = NCAP;
    if (cnt == 0) {
        for (int k = tid; k < TOPK * 5; k += NTHREADS) o[k] = 0.0f;
        return;
    }
    for (int i = cnt + tid; i < NCAP; i += NTHREADS) s_buf[i] = 0;   // pad sinks

    // ---- 2. bitonic sort 1024 u64 keys, descending ----
    for (int k = 2; k <= NCAP; k <<= 1) {
        for (int j = k >> 1; j > 0; j >>= 1) {
            __syncthreads();
            for (int i = tid; i < NCAP; i += NTHREADS) {
                int ix = i ^ j;
                if (ix > i) {
                    uint64_t a = s_buf[i], c = s_buf[ix];
                    bool dir = ((i & k) == 0);           // descending region
                    bool sw  = dir ? (c > a) : (c < a);
                    if (sw) { s_buf[i] = c; s_buf[ix] = a; }
                }
            }
        }
    }
    __syncthreads();

    const int M    = cnt < MCAND ? cnt : MCAND;
    const int kmax = (M + 63) >> 6;

    // ---- 3. gather boxes + scores (keys consumed; s_buf freed for bitmask) ----
    for (int i = tid; i < M; i += NTHREADS) {
        uint64_t key = s_buf[i];
        int p = (int)(~(uint32_t)key);
        s_score[i] = __uint_as_float((uint32_t)(key >> 32));
        s_box[i]   = ((const float4*)locb)[p];
    }
    __syncthreads();

    // ---- 4. IoU bitmask matrix: row i, word k -> 64 suppress bits via ballot ----
    {
        const int wid = tid >> 6;
        const int lid = tid & 63;
        for (int i = wid; i < M; i += (NTHREADS / 64)) {
            float4 bi = s_box[i];                       // wave-uniform read
            float  ai = (bi.z - bi.x) * (bi.w - bi.y);
            int k0 = i >> 6;                            // words k<k0 are all j<i
            for (int k = k0; k < kmax; ++k) {
                int j = (k << 6) + lid;
                float4 bj = s_box[j];                   // j<640 in-bounds; garbage masked below
                float  aj = (bj.z - bj.x) * (bj.w - bj.y);
                float xx1 = fmaxf(bi.x, bj.x);
                float yy1 = fmaxf(bi.y, bj.y);
                float xx2 = fminf(bi.z, bj.z);
                float yy2 = fminf(bi.w, bj.w);
                float ww  = fmaxf(xx2 - xx1, 0.0f);
                float hh  = fmaxf(yy2 - yy1, 0.0f);
                float inter = ww * hh;
                float den   = (ai + aj) - inter;        // ref assoc order
                float iou   = inter / den;              // IEEE div, matches ref
                bool sup = (iou > NMS_T) & (j > i) & (j < M);
                uint64_t m = __ballot(sup);
                if (lid == 0) s_buf[i * 10 + k] = m;
            }
        }
    }
    __syncthreads();

    // ---- 5. greedy scan: one wave, supp word w in lane w, readlane broadcast ----
    if (tid < 64) {
        const int w = (tid < 10) ? tid : 0;             // lanes >=10 shadow word 0
        uint64_t rb[8];
        #pragma unroll
        for (int d = 0; d < 8; ++d) rb[d] = (d < M) ? s_buf[d * 10 + w] : 0;
        uint64_t supp = 0;
        for (int i0 = 0; i0 < M; i0 += 8) {
            #pragma unroll
            for (int d = 0; d < 8; ++d) {
                int i = i0 + d;
                if (i < M) {                             // uniform guard
                    uint64_t row = rb[d];
                    if (w < (i >> 6)) row = 0;           // words below k0 unwritten
                    int ip = i + 8;                      // prefetch 8 ahead into rb[d]
                    if (ip < M) rb[d] = s_buf[ip * 10 + w]; else rb[d] = 0;
                    unsigned part  = (unsigned)(supp >> (i & 32));
                    unsigned wordv = (unsigned)__builtin_amdgcn_readlane((int)part, i >> 6);
                    if (!((wordv >> (i & 31)) & 1u)) supp |= row;   // uniform branch
                }
            }
        }
        if (tid < 10) s_suppw[tid] = supp;
    }
    __syncthreads();

    // ---- 6. keep words + prefix popcounts ----
    if (tid == 0) {
        int total = 0;
        for (int w = 0; w < 10; ++w) {
            uint64_t kw = 0;
            if (w < kmax) {
                int rem = M - (w << 6);
                uint64_t vm = (rem >= 64) ? ~0ull : ((1ull << rem) - 1ull);
                kw = (~s_suppw[w]) & vm;
            }
            s_keepw[w]  = kw;
            s_prefix[w] = total;
            total += __popcll(kw);
        }
        s_n = total < TOPK ? total : TOPK;
    }
    __syncthreads();

    // ---- 7. output: defaults for empty slots, rank-scatter for kept ----
    const int n  = s_n;
    const int fp = s_fp;
    float4 fbox = ((const float4*)locb)[fp];
    for (int k = tid; k < TOPK; k += NTHREADS) {
        if (k >= n) {
            o[k * 5 + 0] = 0.0f;
            o[k * 5 + 1] = fbox.x; o[k * 5 + 2] = fbox.y;
            o[k * 5 + 3] = fbox.z; o[k * 5 + 4] = fbox.w;
        }
    }
    for (int t = tid; t < M; t += NTHREADS) {
        uint64_t kw = s_keepw[t >> 6];
        if ((kw >> (t & 63)) & 1ull) {
            int r = s_prefix[t >> 6] + __popcll(kw & ((1ull << (t & 63)) - 1ull));
            if (r < TOPK) {
                float4 bx = s_box[t];
                o[r * 5 + 0] = s_score[t];
                o[r * 5 + 1] = bx.x; o[r * 5 + 2] = bx.y;
                o[r * 5 + 3] = bx.z; o[r * 5 + 4] = bx.w;
            }
        }
    }
}

extern "C" void kernel_launch(void* const* d_in, const int* in_sizes, int n_in,
                              void* d_out, int out_size, void* d_ws, size_t ws_size,
                              hipStream_t stream) {
    const float* loc  = (const float*)d_in[0];   // [8, 8732, 4]
    const float* conf = (const float*)d_in[1];   // [8, 8732, 21]
    // d_in[2] (prior_data) unused by the reference computation.
    float* out = (float*)d_out;                  // [8, 21, 200, 5]
    detect_kernel<<<dim3(B_BATCH * C_CLASSES), dim3(NTHREADS), 0, stream>>>(loc, conf, out);
}